// Round 8
// baseline (269.916 us; speedup 1.0000x reference)
//
#include <hip/hip_runtime.h>
#include <hip/hip_bf16.h>

typedef __attribute__((ext_vector_type(8))) short bf16x8;
typedef __attribute__((ext_vector_type(16))) float f32x16;

#define TH 0.01f
#define MFMA32(a, b, c) __builtin_amdgcn_mfma_f32_32x32x16_bf16(a, b, c, 0, 0, 0)

constexpr int D = 512, F = 2048, BM = 128, NC = 64;  // FC=32 hcols/chunk
constexpr int KR = 29;                               // k-steps in registers

// LDS map (160256 B dynamic)
constexpr int W1A_O = 0;        // w1 chunk slot 0        32 KB
constexpr int W1B_O = 32768;    // w1 chunk slot 1        32 KB
constexpr int W2A_O = 65536;    // w2 chunk slot 0        32 KB  (x slab
constexpr int W2B_O = 98304;    // w2 chunk slot 1        32 KB   in prologue)
constexpr int H2_0  = 131072;   // h octet-major buf 0     8 KB  [4][128][8]bf16
constexpr int H2_1  = 139264;   // h octet-major buf 1     8 KB
constexpr int SPK_O = 147456;   // spike u32[128]        512 B
constexpr int XSL_O = 147968;   // x slice [128][48] bf16 12 KB  (k 464..511)
constexpr int LDS_TOTAL = 160256;

static __device__ __forceinline__ short f2bf(float f) {
  union { float f; unsigned u; } v; v.f = f;
  unsigned r = v.u + 0x7FFFu + ((v.u >> 16) & 1u);  // RNE
  return (short)(r >> 16);
}

static __device__ __forceinline__ void gl16(const void* g, char* l) {
  __builtin_amdgcn_global_load_lds(
      (const __attribute__((address_space(1))) unsigned*)g,
      (__attribute__((address_space(3))) unsigned*)l, 16, 0, 0);
}

// ---------------------------------------------------------------------------
// Fragment-major staged layouts (32x32x16 MFMA; A/B frag: lane l: idx=l&31,
// k = 8*(l>>5)+j). Every main-loop weight ds_read is LINEAR in lane.
// w1s: 64 regions (chunk c) x 32KB: granule g: ks=g>>6 (0..31), lane=g&63;
//      elems j: w1[ks*16 + (lane>>5)*8 + j][c*32 + (lane&31)]
// w2s: 64 regions x 32KB: granule g: ks=g>>10 (0..1), cf=(g>>6)&15, lane=g&63;
//      elems j: w2[c*32 + ks*16 + (lane>>5)*8 + j][cf*32 + (lane&31)]
// ---------------------------------------------------------------------------
__global__ void prep_weights(const float* __restrict__ w1, const float* __restrict__ w2,
                             short* __restrict__ w1s, short* __restrict__ w2s) {
  int G = blockIdx.x * 256 + threadIdx.x;
  if (G < 131072) {
    int c = G >> 11, g = G & 2047;
    int ks = g >> 6, lane = g & 63, l31 = lane & 31, l5 = lane >> 5;
    bf16x8 v;
#pragma unroll
    for (int j = 0; j < 8; ++j)
      v[j] = f2bf(w1[(size_t)(ks * 16 + l5 * 8 + j) * F + c * 32 + l31]);
    *(bf16x8*)(w1s + (size_t)G * 8) = v;
  } else {
    int H = G - 131072;
    int c = H >> 11, g = H & 2047;
    int ks = g >> 10, cf = (g >> 6) & 15, lane = g & 63, l31 = lane & 31, l5 = lane >> 5;
    bf16x8 v;
#pragma unroll
    for (int j = 0; j < 8; ++j)
      v[j] = f2bf(w2[(size_t)(c * 32 + ks * 16 + l5 * 8 + j) * D + cf * 32 + l31]);
    *(bf16x8*)(w2s + (size_t)H * 8) = v;
  }
}

// C-waves (512 threads, t2=tid-256) stage one 32KB slot: 4 x 16B per thread.
#define CISSUE(loff, gptr)                                                      \
  do {                                                                          \
    _Pragma("unroll") for (int _t = 0; _t < 4; ++_t)                            \
        gl16((const char*)(gptr) + (size_t)(_t * 512 + t2) * 16,                \
             smem + (loff) + (_t * 512 + t2) * 16);                             \
  } while (0)

__global__ __launch_bounds__(768)
__attribute__((amdgpu_waves_per_eu(3, 3)))
void ffn_fused(const float* __restrict__ x,
               const float* __restrict__ b1,
               const float* __restrict__ b2,
               const char* __restrict__ w1g,
               const char* __restrict__ w2g,
               float* __restrict__ out) {
  extern __shared__ char smem[];
  unsigned* spk = (unsigned*)(smem + SPK_O);

  const int tid = threadIdx.x;
  const int lane = tid & 63, wid = tid >> 6;
  const int l31 = lane & 31, l5 = lane >> 5;
  const int row0 = blockIdx.x * BM;

  // ---------------- prologue ----------------
  if (tid >= 256) {  // C: issue w1[0] -> W1A immediately
    int t2 = tid - 256;
    CISSUE(W1A_O, w1g);
  }

  if (wid < 4) {
    // ================= P: producer (GEMM1), 4 waves, 32 rows each =========
    bf16x8 xr[KR];
    bool any = false;
    // x -> swizzled f32 slab (W2A/W2B region) -> owner's regs + x-slice LDS
    for (int r = 0; r < 4; ++r) {
      {  // all 256 P-threads load rows r*32..+31 coalesced
        const float* xg = x + (size_t)(row0 + r * 32) * D;
        float* xs = (float*)(smem + W2A_O);
#pragma unroll
        for (int it = 0; it < 16; ++it) {
          int f = it * 1024 + tid * 4;
          int rl = f >> 9, col = f & 511;
          float4 v = *(const float4*)(xg + rl * 512 + col);
          *(float4*)(xs + rl * 512 + (col ^ ((rl & 7) << 2))) = v;
        }
        asm volatile("s_waitcnt vmcnt(0) lgkmcnt(0)" ::: "memory");
      }
      __builtin_amdgcn_s_barrier();
      {  // all P-threads: slab -> x-slice (k 464..511) as bf16
        const float* xs = (const float*)(smem + W2A_O);
        short* xsl = (short*)(smem + XSL_O);
        int rl = tid >> 3, u2 = (tid & 7) * 2;   // row-local, kk pair
#pragma unroll
        for (int s2 = 0; s2 < 3; ++s2) {
          int col = 464 + s2 * 16 + u2;
          int cs = col ^ ((rl & 7) << 2);
          float2 fv = *(const float2*)(xs + rl * 512 + cs);
          unsigned pk = (unsigned)(unsigned short)f2bf(fv.x) |
                        ((unsigned)(unsigned short)f2bf(fv.y) << 16);
          *(unsigned*)&xsl[(r * 32 + rl) * 48 + s2 * 16 + u2] = pk;
        }
      }
      if (wid == r) {  // owner wave: slab -> bf16 frags + spike (all 32 ksteps)
        const float* xs = (const float*)(smem + W2A_O);
#pragma unroll
        for (int ks = 0; ks < 32; ++ks) {
          int base = 16 * ks + 8 * l5;
          int c0 = base ^ ((l31 & 7) << 2);
          int c1 = (base + 4) ^ ((l31 & 7) << 2);
          float4 a4 = *(const float4*)(xs + l31 * 512 + c0);
          float4 b4 = *(const float4*)(xs + l31 * 512 + c1);
          any = any | (fabsf(a4.x) > TH) | (fabsf(a4.y) > TH) | (fabsf(a4.z) > TH) |
                (fabsf(a4.w) > TH) | (fabsf(b4.x) > TH) | (fabsf(b4.y) > TH) |
                (fabsf(b4.z) > TH) | (fabsf(b4.w) > TH);
          if (ks < KR) {
            bf16x8 t;
            t[0] = f2bf(a4.x); t[1] = f2bf(a4.y); t[2] = f2bf(a4.z); t[3] = f2bf(a4.w);
            t[4] = f2bf(b4.x); t[5] = f2bf(b4.y); t[6] = f2bf(b4.z); t[7] = f2bf(b4.w);
            xr[ks] = t;
          }
        }
      }
      asm volatile("s_waitcnt lgkmcnt(0)" ::: "memory");
      __builtin_amdgcn_s_barrier();
    }
    {  // spike mask for this wave's 32 rows
      unsigned am = any ? 1u : 0u;
      am |= __shfl_xor(am, 32, 64);
      if (lane < 32) spk[wid * 32 + lane] = am;
    }
    __builtin_amdgcn_s_barrier();  // #9: w1[0] landed (C drained), spk visible

    // ---- P main loop: one barrier per chunk ----
    const short* xsl = (const short*)(smem + XSL_O);
    for (int i = 0; i < NC; ++i) {
      const int sl = i & 1;
      const char* w1slot = smem + (sl ? W1B_O : W1A_O);
      char* h2w = smem + (sl ? H2_1 : H2_0);
      // bias loads early: L2-resident, latency hidden under MFMA
      float4 bv0 = *(const float4*)&b1[i * 32 + 0 * 8 + l5 * 4];
      float4 bv1 = *(const float4*)&b1[i * 32 + 1 * 8 + l5 * 4];
      float4 bv2 = *(const float4*)&b1[i * 32 + 2 * 8 + l5 * 4];
      float4 bv3 = *(const float4*)&b1[i * 32 + 3 * 8 + l5 * 4];
      f32x16 hacc;
#pragma unroll
      for (int j = 0; j < 16; ++j) hacc[j] = 0.f;
      __builtin_amdgcn_s_setprio(1);
#pragma unroll
      for (int ks = 0; ks < KR; ++ks) {
        bf16x8 wf = *(const bf16x8*)(w1slot + ks * 1024 + lane * 16);
        hacc = MFMA32(wf, xr[ks], hacc);
      }
#pragma unroll
      for (int s2 = 0; s2 < 3; ++s2) {  // k-steps 29..31 from x-slice
        bf16x8 xf = *(const bf16x8*)(xsl + (wid * 32 + l31) * 48 + s2 * 16 + l5 * 8);
        bf16x8 wf = *(const bf16x8*)(w1slot + (KR + s2) * 1024 + lane * 16);
        hacc = MFMA32(wf, xf, hacc);
      }
      __builtin_amdgcn_s_setprio(0);
      // bias + relu + pack -> h2[oct q][row][8]
      const int hrow = wid * 32 + l31;
      {
        short4 pk;
        pk.x = f2bf(fmaxf(hacc[0] + bv0.x, 0.f));
        pk.y = f2bf(fmaxf(hacc[1] + bv0.y, 0.f));
        pk.z = f2bf(fmaxf(hacc[2] + bv0.z, 0.f));
        pk.w = f2bf(fmaxf(hacc[3] + bv0.w, 0.f));
        *(short4*)(h2w + 0 * 2048 + hrow * 16 + l5 * 8) = pk;
        pk.x = f2bf(fmaxf(hacc[4] + bv1.x, 0.f));
        pk.y = f2bf(fmaxf(hacc[5] + bv1.y, 0.f));
        pk.z = f2bf(fmaxf(hacc[6] + bv1.z, 0.f));
        pk.w = f2bf(fmaxf(hacc[7] + bv1.w, 0.f));
        *(short4*)(h2w + 1 * 2048 + hrow * 16 + l5 * 8) = pk;
        pk.x = f2bf(fmaxf(hacc[8] + bv2.x, 0.f));
        pk.y = f2bf(fmaxf(hacc[9] + bv2.y, 0.f));
        pk.z = f2bf(fmaxf(hacc[10] + bv2.z, 0.f));
        pk.w = f2bf(fmaxf(hacc[11] + bv2.w, 0.f));
        *(short4*)(h2w + 2 * 2048 + hrow * 16 + l5 * 8) = pk;
        pk.x = f2bf(fmaxf(hacc[12] + bv3.x, 0.f));
        pk.y = f2bf(fmaxf(hacc[13] + bv3.y, 0.f));
        pk.z = f2bf(fmaxf(hacc[14] + bv3.z, 0.f));
        pk.w = f2bf(fmaxf(hacc[15] + bv3.w, 0.f));
        *(short4*)(h2w + 3 * 2048 + hrow * 16 + l5 * 8) = pk;
      }
      asm volatile("s_waitcnt lgkmcnt(0)" ::: "memory");
      __builtin_amdgcn_s_barrier();
    }
  } else {
    // ================= C: consumer (GEMM2), 8 waves, 64 rows x 128 dcols ==
    const int t2 = tid - 256;
    const int p  = (wid - 4) & 1;   // row half
    const int q4 = (wid - 4) >> 1;  // dcol quad

    // match P's 9 prologue barriers; drain w1[0] first
    asm volatile("s_waitcnt vmcnt(0) lgkmcnt(0)" ::: "memory");
#pragma unroll
    for (int r = 0; r < 9; ++r) __builtin_amdgcn_s_barrier();

    f32x16 oacc[8];
#pragma unroll
    for (int n = 0; n < 8; ++n)
#pragma unroll
      for (int j = 0; j < 16; ++j) oacc[n][j] = 0.f;

    for (int i = 0; i < NC; ++i) {
      const int sl = i & 1;
      if (i < NC - 1) CISSUE(sl ? W1A_O : W1B_O, w1g + (size_t)(i + 1) * 32768);
      CISSUE(sl ? W2B_O : W2A_O, w2g + (size_t)i * 32768);
      if (i > 0) {
        const char* h2r  = smem + (sl ? H2_0 : H2_1);
        const char* w2rd = smem + (sl ? W2A_O : W2B_O);
        __builtin_amdgcn_s_setprio(1);
#pragma unroll
        for (int ks = 0; ks < 2; ++ks) {
          bf16x8 hA0 = *(const bf16x8*)(h2r + ((2 * ks + l5) * 128 + p * 64 + l31) * 16);
          bf16x8 hA1 = *(const bf16x8*)(h2r + ((2 * ks + l5) * 128 + p * 64 + 32 + l31) * 16);
#pragma unroll
          for (int n = 0; n < 4; ++n) {
            bf16x8 wf = *(const bf16x8*)(w2rd + ks * 16384 + (q4 * 4 + n) * 1024 + lane * 16);
            oacc[n]     = MFMA32(hA0, wf, oacc[n]);
            oacc[4 + n] = MFMA32(hA1, wf, oacc[4 + n]);
          }
        }
        __builtin_amdgcn_s_setprio(0);
      }
      asm volatile("s_waitcnt vmcnt(0) lgkmcnt(0)" ::: "memory");
      __builtin_amdgcn_s_barrier();
    }

    // epilogue: G2 chunk 63 (h2[1], W2B) + bias + spike + store
    {
      const char* h2r  = smem + H2_1;
      const char* w2rd = smem + W2B_O;
      __builtin_amdgcn_s_setprio(1);
#pragma unroll
      for (int ks = 0; ks < 2; ++ks) {
        bf16x8 hA0 = *(const bf16x8*)(h2r + ((2 * ks + l5) * 128 + p * 64 + l31) * 16);
        bf16x8 hA1 = *(const bf16x8*)(h2r + ((2 * ks + l5) * 128 + p * 64 + 32 + l31) * 16);
#pragma unroll
        for (int n = 0; n < 4; ++n) {
          bf16x8 wf = *(const bf16x8*)(w2rd + ks * 16384 + (q4 * 4 + n) * 1024 + lane * 16);
          oacc[n]     = MFMA32(hA0, wf, oacc[n]);
          oacc[4 + n] = MFMA32(hA1, wf, oacc[4 + n]);
        }
      }
      __builtin_amdgcn_s_setprio(0);
    }
#pragma unroll
    for (int rfi = 0; rfi < 2; ++rfi) {
#pragma unroll
      for (int n = 0; n < 4; ++n) {
        int dcol = q4 * 128 + n * 32 + l31;
        float bias = b2[dcol];
        f32x16 acc = oacc[rfi * 4 + n];
#pragma unroll
        for (int r = 0; r < 16; ++r) {
          int row = p * 64 + rfi * 32 + (r & 3) + 8 * (r >> 2) + 4 * l5;
          float v = acc[r] + bias;
          out[(size_t)(row0 + row) * D + dcol] = spk[row] ? v : 0.f;
        }
      }
    }
  }
}

extern "C" void kernel_launch(void* const* d_in, const int* in_sizes, int n_in,
                              void* d_out, int out_size, void* d_ws, size_t ws_size,
                              hipStream_t stream) {
  const float* x  = (const float*)d_in[0];
  const float* w1 = (const float*)d_in[1];
  const float* b1 = (const float*)d_in[2];
  const float* w2 = (const float*)d_in[3];
  const float* b2 = (const float*)d_in[4];
  float* out = (float*)d_out;

  short* w1staged = (short*)d_ws;               // 2 MB
  short* w2staged = w1staged + (size_t)D * F;   // 2 MB

  prep_weights<<<1024, 256, 0, stream>>>(w1, w2, w1staged, w2staged);

  (void)hipFuncSetAttribute((const void*)ffn_fused,
                            hipFuncAttributeMaxDynamicSharedMemorySize, LDS_TOTAL);
  int M = out_size / D;  // 32768
  ffn_fused<<<M / BM, 768, LDS_TOTAL, stream>>>(x, b1, b2, (const char*)w1staged,
                                                (const char*)w2staged, out);
}

// Round 9
// 265.309 us; speedup vs baseline: 1.0174x; 1.0174x over previous
//
#include <hip/hip_runtime.h>
#include <hip/hip_bf16.h>

typedef __attribute__((ext_vector_type(8))) short bf16x8;
typedef __attribute__((ext_vector_type(16))) float f32x16;

#define TH 0.01f
#define MFMA32(a, b, c) __builtin_amdgcn_mfma_f32_32x32x16_bf16(a, b, c, 0, 0, 0)

constexpr int D = 512, F = 2048, BM = 128, NC = 64;  // FC=32 hcols/chunk

// LDS map (147968 B dynamic)
constexpr int W1A_O = 0;        // w1 chunk slot 0        32 KB
constexpr int W1B_O = 32768;    // w1 chunk slot 1        32 KB
constexpr int W2A_O = 65536;    // w2 chunk slot 0        32 KB  (x slab
constexpr int W2B_O = 98304;    // w2 chunk slot 1        32 KB   in prologue)
constexpr int H2_0  = 131072;   // h octet-major buf 0     8 KB  [4][128][8]bf16
constexpr int H2_1  = 139264;   // h octet-major buf 1     8 KB
constexpr int SPK_O = 147456;   // spike u32[128]        512 B
constexpr int LDS_TOTAL = 147968;

static __device__ __forceinline__ short f2bf(float f) {
  union { float f; unsigned u; } v; v.f = f;
  unsigned r = v.u + 0x7FFFu + ((v.u >> 16) & 1u);  // RNE
  return (short)(r >> 16);
}

static __device__ __forceinline__ void gl16(const void* g, char* l) {
  __builtin_amdgcn_global_load_lds(
      (const __attribute__((address_space(1))) unsigned*)g,
      (__attribute__((address_space(3))) unsigned*)l, 16, 0, 0);
}

// ---------------------------------------------------------------------------
// Fragment-major staged layouts (32x32x16 MFMA; A/B frag: lane l: idx=l&31,
// k = 8*(l>>5)+j). Every main-loop weight ds_read is LINEAR in lane.
// w1s: 64 regions (chunk c) x 32KB: granule g: ks=g>>6 (0..31), lane=g&63;
//      elems j: w1[ks*16 + (lane>>5)*8 + j][c*32 + (lane&31)]
// w2s: 64 regions x 32KB: granule g: ks=g>>10 (0..1), cf=(g>>6)&15, lane=g&63;
//      elems j: w2[c*32 + ks*16 + (lane>>5)*8 + j][cf*32 + (lane&31)]
// ---------------------------------------------------------------------------
__global__ void prep_weights(const float* __restrict__ w1, const float* __restrict__ w2,
                             short* __restrict__ w1s, short* __restrict__ w2s) {
  int G = blockIdx.x * 256 + threadIdx.x;
  if (G < 131072) {
    int c = G >> 11, g = G & 2047;
    int ks = g >> 6, lane = g & 63, l31 = lane & 31, l5 = lane >> 5;
    bf16x8 v;
#pragma unroll
    for (int j = 0; j < 8; ++j)
      v[j] = f2bf(w1[(size_t)(ks * 16 + l5 * 8 + j) * F + c * 32 + l31]);
    *(bf16x8*)(w1s + (size_t)G * 8) = v;
  } else {
    int H = G - 131072;
    int c = H >> 11, g = H & 2047;
    int ks = g >> 10, cf = (g >> 6) & 15, lane = g & 63, l31 = lane & 31, l5 = lane >> 5;
    bf16x8 v;
#pragma unroll
    for (int j = 0; j < 8; ++j)
      v[j] = f2bf(w2[(size_t)(c * 32 + ks * 16 + l5 * 8 + j) * D + cf * 32 + l31]);
    *(bf16x8*)(w2s + (size_t)H * 8) = v;
  }
}

// C-waves (512 threads, t2=tid-256) stage one 32KB slot: 4 x 16B per thread.
#define CISSUE(loff, gptr)                                                      \
  do {                                                                          \
    _Pragma("unroll") for (int _t = 0; _t < 4; ++_t)                            \
        gl16((const char*)(gptr) + (size_t)(_t * 512 + t2) * 16,                \
             smem + (loff) + (_t * 512 + t2) * 16);                             \
  } while (0)

__global__ __launch_bounds__(768, 1)
void ffn_fused(const float* __restrict__ x,
               const float* __restrict__ b1,
               const float* __restrict__ b2,
               const char* __restrict__ w1g,
               const char* __restrict__ w2g,
               float* __restrict__ out) {
  extern __shared__ char smem[];
  unsigned* spk = (unsigned*)(smem + SPK_O);

  const int tid = threadIdx.x;
  const int lane = tid & 63, wid = tid >> 6;
  const int l31 = lane & 31, l5 = lane >> 5;
  const int row0 = blockIdx.x * BM;

  // ---------------- prologue ----------------
  if (tid >= 256) {  // C: issue w1[0] -> W1A immediately
    int t2 = tid - 256;
    CISSUE(W1A_O, w1g);
  }

  if (wid < 4) {
    // ================= P: producer (GEMM1), 4 waves, 32 rows each =========
    bf16x8 xr[32];
    bool any = false;
    // x -> swizzled f32 slab (W2A/W2B region) -> owner wave's regs
    for (int r = 0; r < 4; ++r) {
      {  // all 256 P-threads load rows r*32..+31 coalesced
        const float* xg = x + (size_t)(row0 + r * 32) * D;
        float* xs = (float*)(smem + W2A_O);
#pragma unroll
        for (int it = 0; it < 16; ++it) {
          int f = it * 1024 + tid * 4;
          int rl = f >> 9, col = f & 511;
          float4 v = *(const float4*)(xg + rl * 512 + col);
          *(float4*)(xs + rl * 512 + (col ^ ((rl & 7) << 2))) = v;
        }
        asm volatile("s_waitcnt vmcnt(0) lgkmcnt(0)" ::: "memory");
      }
      __builtin_amdgcn_s_barrier();
      if (wid == r) {  // owner wave: slab -> bf16 frags + spike
        const float* xs = (const float*)(smem + W2A_O);
#pragma unroll
        for (int ks = 0; ks < 32; ++ks) {
          int base = 16 * ks + 8 * l5;
          int c0 = base ^ ((l31 & 7) << 2);
          int c1 = (base + 4) ^ ((l31 & 7) << 2);
          float4 a4 = *(const float4*)(xs + l31 * 512 + c0);
          float4 b4 = *(const float4*)(xs + l31 * 512 + c1);
          any = any | (fabsf(a4.x) > TH) | (fabsf(a4.y) > TH) | (fabsf(a4.z) > TH) |
                (fabsf(a4.w) > TH) | (fabsf(b4.x) > TH) | (fabsf(b4.y) > TH) |
                (fabsf(b4.z) > TH) | (fabsf(b4.w) > TH);
          bf16x8 t;
          t[0] = f2bf(a4.x); t[1] = f2bf(a4.y); t[2] = f2bf(a4.z); t[3] = f2bf(a4.w);
          t[4] = f2bf(b4.x); t[5] = f2bf(b4.y); t[6] = f2bf(b4.z); t[7] = f2bf(b4.w);
          xr[ks] = t;
        }
      }
      asm volatile("s_waitcnt lgkmcnt(0)" ::: "memory");
      __builtin_amdgcn_s_barrier();
    }
    {  // spike mask for this wave's 32 rows
      unsigned am = any ? 1u : 0u;
      am |= __shfl_xor(am, 32, 64);
      if (lane < 32) spk[wid * 32 + lane] = am;
    }
    __builtin_amdgcn_s_barrier();  // #9: w1[0] landed (C drained), spk visible

    // ---- P main loop: one barrier per chunk ----
    for (int i = 0; i < NC; ++i) {
      const int sl = i & 1;
      const char* w1slot = smem + (sl ? W1B_O : W1A_O);
      char* h2w = smem + (sl ? H2_1 : H2_0);
      // bias loads early: L2-resident, latency hidden under MFMA
      float4 bv0 = *(const float4*)&b1[i * 32 + 0 * 8 + l5 * 4];
      float4 bv1 = *(const float4*)&b1[i * 32 + 1 * 8 + l5 * 4];
      float4 bv2 = *(const float4*)&b1[i * 32 + 2 * 8 + l5 * 4];
      float4 bv3 = *(const float4*)&b1[i * 32 + 3 * 8 + l5 * 4];
      f32x16 hacc;
#pragma unroll
      for (int j = 0; j < 16; ++j) hacc[j] = 0.f;
      __builtin_amdgcn_s_setprio(1);
#pragma unroll
      for (int ks = 0; ks < 32; ++ks) {
        bf16x8 wf = *(const bf16x8*)(w1slot + ks * 1024 + lane * 16);
        hacc = MFMA32(wf, xr[ks], hacc);
      }
      __builtin_amdgcn_s_setprio(0);
      // bias + relu + pack -> h2[oct q][row][8]
      const int hrow = wid * 32 + l31;
      {
        short4 pk;
        pk.x = f2bf(fmaxf(hacc[0] + bv0.x, 0.f));
        pk.y = f2bf(fmaxf(hacc[1] + bv0.y, 0.f));
        pk.z = f2bf(fmaxf(hacc[2] + bv0.z, 0.f));
        pk.w = f2bf(fmaxf(hacc[3] + bv0.w, 0.f));
        *(short4*)(h2w + 0 * 2048 + hrow * 16 + l5 * 8) = pk;
        pk.x = f2bf(fmaxf(hacc[4] + bv1.x, 0.f));
        pk.y = f2bf(fmaxf(hacc[5] + bv1.y, 0.f));
        pk.z = f2bf(fmaxf(hacc[6] + bv1.z, 0.f));
        pk.w = f2bf(fmaxf(hacc[7] + bv1.w, 0.f));
        *(short4*)(h2w + 1 * 2048 + hrow * 16 + l5 * 8) = pk;
        pk.x = f2bf(fmaxf(hacc[8] + bv2.x, 0.f));
        pk.y = f2bf(fmaxf(hacc[9] + bv2.y, 0.f));
        pk.z = f2bf(fmaxf(hacc[10] + bv2.z, 0.f));
        pk.w = f2bf(fmaxf(hacc[11] + bv2.w, 0.f));
        *(short4*)(h2w + 2 * 2048 + hrow * 16 + l5 * 8) = pk;
        pk.x = f2bf(fmaxf(hacc[12] + bv3.x, 0.f));
        pk.y = f2bf(fmaxf(hacc[13] + bv3.y, 0.f));
        pk.z = f2bf(fmaxf(hacc[14] + bv3.z, 0.f));
        pk.w = f2bf(fmaxf(hacc[15] + bv3.w, 0.f));
        *(short4*)(h2w + 3 * 2048 + hrow * 16 + l5 * 8) = pk;
      }
      asm volatile("s_waitcnt lgkmcnt(0)" ::: "memory");
      __builtin_amdgcn_s_barrier();
    }
  } else {
    // ================= C: consumer (GEMM2), 8 waves, 64 rows x 128 dcols ==
    const int t2 = tid - 256;
    const int p  = (wid - 4) & 1;   // row half
    const int q4 = (wid - 4) >> 1;  // dcol quad

    // match P's 9 prologue barriers; drain w1[0] first
    asm volatile("s_waitcnt vmcnt(0) lgkmcnt(0)" ::: "memory");
#pragma unroll
    for (int r = 0; r < 9; ++r) __builtin_amdgcn_s_barrier();

    f32x16 oacc[8];
#pragma unroll
    for (int n = 0; n < 8; ++n)
#pragma unroll
      for (int j = 0; j < 16; ++j) oacc[n][j] = 0.f;

    for (int i = 0; i < NC; ++i) {
      const int sl = i & 1;
      if (i < NC - 1) CISSUE(sl ? W1A_O : W1B_O, w1g + (size_t)(i + 1) * 32768);
      CISSUE(sl ? W2B_O : W2A_O, w2g + (size_t)i * 32768);
      if (i > 0) {
        const char* h2r  = smem + (sl ? H2_0 : H2_1);
        const char* w2rd = smem + (sl ? W2A_O : W2B_O);
        __builtin_amdgcn_s_setprio(1);
#pragma unroll
        for (int ks = 0; ks < 2; ++ks) {
          bf16x8 hA0 = *(const bf16x8*)(h2r + ((2 * ks + l5) * 128 + p * 64 + l31) * 16);
          bf16x8 hA1 = *(const bf16x8*)(h2r + ((2 * ks + l5) * 128 + p * 64 + 32 + l31) * 16);
#pragma unroll
          for (int n = 0; n < 4; ++n) {
            bf16x8 wf = *(const bf16x8*)(w2rd + ks * 16384 + (q4 * 4 + n) * 1024 + lane * 16);
            oacc[n]     = MFMA32(hA0, wf, oacc[n]);
            oacc[4 + n] = MFMA32(hA1, wf, oacc[4 + n]);
          }
        }
        __builtin_amdgcn_s_setprio(0);
      }
      asm volatile("s_waitcnt vmcnt(0) lgkmcnt(0)" ::: "memory");
      __builtin_amdgcn_s_barrier();
    }

    // epilogue: G2 chunk 63 (h2[1], W2B) + bias + spike + store
    {
      const char* h2r  = smem + H2_1;
      const char* w2rd = smem + W2B_O;
      __builtin_amdgcn_s_setprio(1);
#pragma unroll
      for (int ks = 0; ks < 2; ++ks) {
        bf16x8 hA0 = *(const bf16x8*)(h2r + ((2 * ks + l5) * 128 + p * 64 + l31) * 16);
        bf16x8 hA1 = *(const bf16x8*)(h2r + ((2 * ks + l5) * 128 + p * 64 + 32 + l31) * 16);
#pragma unroll
        for (int n = 0; n < 4; ++n) {
          bf16x8 wf = *(const bf16x8*)(w2rd + ks * 16384 + (q4 * 4 + n) * 1024 + lane * 16);
          oacc[n]     = MFMA32(hA0, wf, oacc[n]);
          oacc[4 + n] = MFMA32(hA1, wf, oacc[4 + n]);
        }
      }
      __builtin_amdgcn_s_setprio(0);
    }
#pragma unroll
    for (int rfi = 0; rfi < 2; ++rfi) {
#pragma unroll
      for (int n = 0; n < 4; ++n) {
        int dcol = q4 * 128 + n * 32 + l31;
        float bias = b2[dcol];
        f32x16 acc = oacc[rfi * 4 + n];
#pragma unroll
        for (int r = 0; r < 16; ++r) {
          int row = p * 64 + rfi * 32 + (r & 3) + 8 * (r >> 2) + 4 * l5;
          float v = acc[r] + bias;
          out[(size_t)(row0 + row) * D + dcol] = spk[row] ? v : 0.f;
        }
      }
    }
  }
}

extern "C" void kernel_launch(void* const* d_in, const int* in_sizes, int n_in,
                              void* d_out, int out_size, void* d_ws, size_t ws_size,
                              hipStream_t stream) {
  const float* x  = (const float*)d_in[0];
  const float* w1 = (const float*)d_in[1];
  const float* b1 = (const float*)d_in[2];
  const float* w2 = (const float*)d_in[3];
  const float* b2 = (const float*)d_in[4];
  float* out = (float*)d_out;

  short* w1staged = (short*)d_ws;               // 2 MB
  short* w2staged = w1staged + (size_t)D * F;   // 2 MB

  prep_weights<<<1024, 256, 0, stream>>>(w1, w2, w1staged, w2staged);

  (void)hipFuncSetAttribute((const void*)ffn_fused,
                            hipFuncAttributeMaxDynamicSharedMemorySize, LDS_TOTAL);
  int M = out_size / D;  // 32768
  ffn_fused<<<M / BM, 768, LDS_TOTAL, stream>>>(x, b1, b2, (const char*)w1staged,
                                                (const char*)w2staged, out);
}

// Round 10
// 167.794 us; speedup vs baseline: 1.6086x; 1.5812x over previous
//
#include <hip/hip_runtime.h>
#include <hip/hip_bf16.h>

typedef __attribute__((ext_vector_type(8))) short bf16x8;
typedef __attribute__((ext_vector_type(16))) float f32x16;
typedef __attribute__((ext_vector_type(4))) unsigned u32x4;

#define TH 0.01f
#define MFMA32(a, b, c) __builtin_amdgcn_mfma_f32_32x32x16_bf16(a, b, c, 0, 0, 0)

constexpr int D = 512, F = 2048, BM = 128, NC = 64;  // FC=32 hcols/chunk

// LDS map (163840 B = full 160 KiB)
constexpr int W1A_O = 0;        // w1 chunk slot 0          32 KB
constexpr int W1B_O = 32768;    // w1 chunk slot 1          32 KB
constexpr int W2A_O = 65536;    // w2 chunk slot 0          32 KB  (x slab in
constexpr int W2B_O = 98304;    // w2 chunk slot 1          32 KB   prologue)
constexpr int H2_0  = 131072;   // h buf 0 [4][128][8]bf16   8 KB  (spike tmp
constexpr int H2_1  = 139264;   // h buf 1                   8 KB   in prologue)
constexpr int HP_O  = 147456;   // bf16 partials [4][64][16] 8 KB
constexpr int B1_O  = 155648;   // b1 f32[2048]              8 KB
constexpr int LDS_TOTAL = 163840;

static __device__ __forceinline__ short f2bf(float f) {
  union { float f; unsigned u; } v; v.f = f;
  unsigned r = v.u + 0x7FFFu + ((v.u >> 16) & 1u);  // RNE
  return (short)(r >> 16);
}

static __device__ __forceinline__ void gl16(const void* g, char* l) {
  __builtin_amdgcn_global_load_lds(
      (const __attribute__((address_space(1))) unsigned*)g,
      (__attribute__((address_space(3))) unsigned*)l, 16, 0, 0);
}

// ---------------------------------------------------------------------------
// Fragment-major staged layouts (32x32x16 MFMA; A/B frag: lane l: idx=l&31,
// k = 8*(l>>5)+j). Every main-loop weight ds_read is LINEAR in lane.
// w1s: 64 regions (chunk c) x 32KB: granule g: ks=g>>6 (0..31), lane=g&63;
//      elems j: w1[ks*16 + (lane>>5)*8 + j][c*32 + (lane&31)]
// w2s: 64 regions x 32KB: granule g: ks=g>>10 (0..1), cf=(g>>6)&15, lane=g&63;
//      elems j: w2[c*32 + ks*16 + (lane>>5)*8 + j][cf*32 + (lane&31)]
// ---------------------------------------------------------------------------
__global__ void prep_weights(const float* __restrict__ w1, const float* __restrict__ w2,
                             short* __restrict__ w1s, short* __restrict__ w2s) {
  int G = blockIdx.x * 256 + threadIdx.x;
  if (G < 131072) {
    int c = G >> 11, g = G & 2047;
    int ks = g >> 6, lane = g & 63, l31 = lane & 31, l5 = lane >> 5;
    bf16x8 v;
#pragma unroll
    for (int j = 0; j < 8; ++j)
      v[j] = f2bf(w1[(size_t)(ks * 16 + l5 * 8 + j) * F + c * 32 + l31]);
    *(bf16x8*)(w1s + (size_t)G * 8) = v;
  } else {
    int H = G - 131072;
    int c = H >> 11, g = H & 2047;
    int ks = g >> 10, cf = (g >> 6) & 15, lane = g & 63, l31 = lane & 31, l5 = lane >> 5;
    bf16x8 v;
#pragma unroll
    for (int j = 0; j < 8; ++j)
      v[j] = f2bf(w2[(size_t)(c * 32 + ks * 16 + l5 * 8 + j) * D + cf * 32 + l31]);
    *(bf16x8*)(w2s + (size_t)H * 8) = v;
  }
}

// all 512 threads stage one 32KB slot: 4 x 16B granules per thread.
#define ISSUE4(loff, gptr)                                                      \
  do {                                                                          \
    _Pragma("unroll") for (int _t = 0; _t < 4; ++_t)                            \
        gl16((const char*)(gptr) + (size_t)(_t * 512 + tid) * 16,               \
             smem + (loff) + (_t * 512 + tid) * 16);                            \
  } while (0)

__global__ __launch_bounds__(512, 2)
void ffn_fused(const float* __restrict__ x,
               const float* __restrict__ b1,
               const float* __restrict__ b2,
               const char* __restrict__ w1g,
               const char* __restrict__ w2g,
               float* __restrict__ out) {
  extern __shared__ char smem[];
  const int tid = threadIdx.x;
  const int lane = tid & 63, wid = tid >> 6;
  const int l31 = lane & 31, l5 = lane >> 5;
  const int row0 = blockIdx.x * BM;

  const int p  = wid >> 1, kh = wid & 1;  // G1 role: pair, k-half
  const int rh = wid & 1,  cq = wid >> 1; // G2 role: row-half, col-quad
  unsigned* tmpspk = (unsigned*)(smem + H2_0);  // prologue-only

  // ---------------- prologue ----------------
  if (tid < 4) tmpspk[tid] = 0u;
  ISSUE4(W1A_O, w1g);  // w1 chunk 0 -> slot 0
  *(float4*)((float*)(smem + B1_O) + tid * 4) = *(const float4*)&b1[tid * 4];

  // x rows -> swizzled f32 slab (W2 slots, free now) -> pair-half regs.
  bf16x8 xr[16];
  for (int r = 0; r < 4; ++r) {
    {
      const float* xg = x + (size_t)(row0 + r * 32) * D;
      float* xs = (float*)(smem + W2A_O);
#pragma unroll
      for (int it = 0; it < 8; ++it) {
        int idx = it * 512 + tid;
        int rl = idx >> 7, col = (idx & 127) * 4;
        float4 v = *(const float4*)(xg + rl * 512 + col);
        *(float4*)(xs + rl * 512 + (col ^ ((rl & 7) << 2))) = v;
      }
    }
    asm volatile("s_waitcnt vmcnt(0) lgkmcnt(0)" ::: "memory");
    __builtin_amdgcn_s_barrier();
    if (p == r) {  // pair r: both k-half waves extract their 16 frags
      const float* xs = (const float*)(smem + W2A_O);
      bool rowany = false;
#pragma unroll
      for (int s = 0; s < 16; ++s) {
        int base = kh * 256 + s * 16 + l5 * 8;
        int c0 = base ^ ((l31 & 7) << 2);
        int c1 = (base + 4) ^ ((l31 & 7) << 2);
        float4 a4 = *(const float4*)(xs + l31 * 512 + c0);
        float4 b4 = *(const float4*)(xs + l31 * 512 + c1);
        rowany = rowany | (fabsf(a4.x) > TH) | (fabsf(a4.y) > TH) |
                 (fabsf(a4.z) > TH) | (fabsf(a4.w) > TH) | (fabsf(b4.x) > TH) |
                 (fabsf(b4.y) > TH) | (fabsf(b4.z) > TH) | (fabsf(b4.w) > TH);
        bf16x8 t;
        t[0] = f2bf(a4.x); t[1] = f2bf(a4.y); t[2] = f2bf(a4.z); t[3] = f2bf(a4.w);
        t[4] = f2bf(b4.x); t[5] = f2bf(b4.y); t[6] = f2bf(b4.z); t[7] = f2bf(b4.w);
        xr[s] = t;
      }
      unsigned long long bl = __ballot(rowany);  // bit l = row (l&31) any
      if (lane == 0) atomicOr(&tmpspk[r], (unsigned)bl | (unsigned)(bl >> 32));
    }
    asm volatile("s_waitcnt lgkmcnt(0)" ::: "memory");
    __builtin_amdgcn_s_barrier();
  }
  // spike masks for this wave's G2 rows (rh*64 .. +63) -> 2 regs
  const unsigned smv0 = tmpspk[rh * 2 + 0];
  const unsigned smv1 = tmpspk[rh * 2 + 1];
  asm volatile("s_waitcnt vmcnt(0) lgkmcnt(0)" ::: "memory");
  __builtin_amdgcn_s_barrier();  // w1[0] landed; H2_0 free

  f32x16 oacc[8];
#pragma unroll
  for (int n = 0; n < 8; ++n)
#pragma unroll
    for (int j = 0; j < 16; ++j) oacc[n][j] = 0.f;

  const float* b1s = (const float*)(smem + B1_O);

  // ---------------- main loop: 64 chunks x 2 phases ----------------
  // A(i): issue w1[i+1], w2[i]; G1(i); odd->hp.  end: vmcnt(8) [drains w2[i-1]]
  // B(i): even: combine+h2[i&1]; all: G2(i-1).   end: vmcnt(4) [drains w1[i+1]]
#pragma unroll 1
  for (int i = 0; i < NC; ++i) {
    const int sl = i & 1;
    // ---- phase A ----
    if (i < NC - 1) ISSUE4(sl ? W1A_O : W1B_O, w1g + (size_t)(i + 1) * 32768);
    ISSUE4(sl ? W2B_O : W2A_O, w2g + (size_t)i * 32768);
    const char* w1slot = smem + (sl ? W1B_O : W1A_O);
    f32x16 hacc;
#pragma unroll
    for (int j = 0; j < 16; ++j) hacc[j] = 0.f;
    __builtin_amdgcn_s_setprio(1);
#pragma unroll
    for (int s = 0; s < 16; ++s) {
      bf16x8 wf = *(const bf16x8*)(w1slot + (kh * 16 + s) * 1024 + lane * 16);
      hacc = MFMA32(wf, xr[s], hacc);
    }
    __builtin_amdgcn_s_setprio(0);
    if (kh) {  // odd half: bf16-pack partial -> hp
      u32x4 pk0, pk1;
#pragma unroll
      for (int t = 0; t < 4; ++t) {
        pk0[t] = (unsigned)(unsigned short)f2bf(hacc[2 * t]) |
                 ((unsigned)(unsigned short)f2bf(hacc[2 * t + 1]) << 16);
        pk1[t] = (unsigned)(unsigned short)f2bf(hacc[8 + 2 * t]) |
                 ((unsigned)(unsigned short)f2bf(hacc[8 + 2 * t + 1]) << 16);
      }
      *(u32x4*)(smem + HP_O + p * 2048 + lane * 32) = pk0;
      *(u32x4*)(smem + HP_O + p * 2048 + lane * 32 + 16) = pk1;
    }
    if (i < NC - 1) asm volatile("s_waitcnt vmcnt(8) lgkmcnt(0)" ::: "memory");
    else            asm volatile("s_waitcnt vmcnt(4) lgkmcnt(0)" ::: "memory");
    __builtin_amdgcn_s_barrier();

    // ---- phase B ----
    if (!kh) {  // even half: combine + bias + relu + pack -> h2[sl]
      const char* hp = smem + HP_O + p * 2048;
      u32x4 q0 = *(const u32x4*)(hp + lane * 32);
      u32x4 q1 = *(const u32x4*)(hp + lane * 32 + 16);
#pragma unroll
      for (int t = 0; t < 4; ++t) {
        hacc[2 * t]     += __uint_as_float(q0[t] << 16);
        hacc[2 * t + 1] += __uint_as_float(q0[t] & 0xffff0000u);
        hacc[8 + 2 * t]     += __uint_as_float(q1[t] << 16);
        hacc[8 + 2 * t + 1] += __uint_as_float(q1[t] & 0xffff0000u);
      }
      char* h2w = smem + (sl ? H2_1 : H2_0);
#pragma unroll
      for (int q = 0; q < 4; ++q) {
        float4 bv = *(const float4*)&b1s[i * 32 + q * 8 + l5 * 4];
        short4 pk;
        pk.x = f2bf(fmaxf(hacc[4 * q + 0] + bv.x, 0.f));
        pk.y = f2bf(fmaxf(hacc[4 * q + 1] + bv.y, 0.f));
        pk.z = f2bf(fmaxf(hacc[4 * q + 2] + bv.z, 0.f));
        pk.w = f2bf(fmaxf(hacc[4 * q + 3] + bv.w, 0.f));
        *(short4*)(h2w + q * 2048 + (p * 32 + l31) * 16 + l5 * 8) = pk;
      }
    }
    if (i > 0) {  // G2 on chunk i-1
      const int js = (i - 1) & 1;
      const char* h2r  = smem + (js ? H2_1 : H2_0);
      const char* w2rd = smem + (js ? W2B_O : W2A_O);
      __builtin_amdgcn_s_setprio(1);
#pragma unroll
      for (int ks = 0; ks < 2; ++ks) {
        bf16x8 hA0 = *(const bf16x8*)(h2r + ((2 * ks + l5) * 128 + rh * 64 + l31) * 16);
        bf16x8 hA1 = *(const bf16x8*)(h2r + ((2 * ks + l5) * 128 + rh * 64 + 32 + l31) * 16);
#pragma unroll
        for (int n = 0; n < 4; ++n) {
          bf16x8 wf = *(const bf16x8*)(w2rd + ks * 16384 + (cq * 4 + n) * 1024 + lane * 16);
          oacc[n]     = MFMA32(hA0, wf, oacc[n]);
          oacc[4 + n] = MFMA32(hA1, wf, oacc[4 + n]);
        }
      }
      __builtin_amdgcn_s_setprio(0);
    }
    if (i < NC - 1) asm volatile("s_waitcnt vmcnt(4) lgkmcnt(0)" ::: "memory");
    else            asm volatile("s_waitcnt vmcnt(0) lgkmcnt(0)" ::: "memory");
    __builtin_amdgcn_s_barrier();
  }

  // ---------------- epilogue: G2 chunk 63 + store ----------------
  {
    const char* h2r  = smem + H2_1;   // 63 & 1 = 1
    const char* w2rd = smem + W2B_O;
    __builtin_amdgcn_s_setprio(1);
#pragma unroll
    for (int ks = 0; ks < 2; ++ks) {
      bf16x8 hA0 = *(const bf16x8*)(h2r + ((2 * ks + l5) * 128 + rh * 64 + l31) * 16);
      bf16x8 hA1 = *(const bf16x8*)(h2r + ((2 * ks + l5) * 128 + rh * 64 + 32 + l31) * 16);
#pragma unroll
      for (int n = 0; n < 4; ++n) {
        bf16x8 wf = *(const bf16x8*)(w2rd + ks * 16384 + (cq * 4 + n) * 1024 + lane * 16);
        oacc[n]     = MFMA32(hA0, wf, oacc[n]);
        oacc[4 + n] = MFMA32(hA1, wf, oacc[4 + n]);
      }
    }
    __builtin_amdgcn_s_setprio(0);
  }
#pragma unroll
  for (int rfi = 0; rfi < 2; ++rfi) {
    unsigned m = rfi ? smv1 : smv0;
#pragma unroll
    for (int n = 0; n < 4; ++n) {
      int dcol = cq * 128 + n * 32 + l31;
      float bias = b2[dcol];
      f32x16 acc = oacc[rfi * 4 + n];
#pragma unroll
      for (int r = 0; r < 16; ++r) {
        int rbit = (r & 3) + 8 * (r >> 2) + 4 * l5;
        int row = rh * 64 + rfi * 32 + rbit;
        float v = acc[r] + bias;
        out[(size_t)(row0 + row) * D + dcol] = ((m >> rbit) & 1u) ? v : 0.f;
      }
    }
  }
}

extern "C" void kernel_launch(void* const* d_in, const int* in_sizes, int n_in,
                              void* d_out, int out_size, void* d_ws, size_t ws_size,
                              hipStream_t stream) {
  const float* x  = (const float*)d_in[0];
  const float* w1 = (const float*)d_in[1];
  const float* b1 = (const float*)d_in[2];
  const float* w2 = (const float*)d_in[3];
  const float* b2 = (const float*)d_in[4];
  float* out = (float*)d_out;

  short* w1staged = (short*)d_ws;               // 2 MB
  short* w2staged = w1staged + (size_t)D * F;   // 2 MB

  prep_weights<<<1024, 256, 0, stream>>>(w1, w2, w1staged, w2staged);

  (void)hipFuncSetAttribute((const void*)ffn_fused,
                            hipFuncAttributeMaxDynamicSharedMemorySize, LDS_TOTAL);
  int M = out_size / D;  // 32768
  ffn_fused<<<M / BM, 512, LDS_TOTAL, stream>>>(x, b1, b2, (const char*)w1staged,
                                                (const char*)w2staged, out);
}